// Round 19
// baseline (185.820 us; speedup 1.0000x reference)
//
#include <hip/hip_runtime.h>
#include <hip/hip_bf16.h>

#define NB 4
#define NT 2048
#define ND 1024
#define NH 16
#define NDH 64
#define NM (NB*NT)   // 8192 rows

typedef __bf16 bf16_t;
typedef bf16_t bf16x4 __attribute__((ext_vector_type(4)));
typedef bf16_t bf16x8 __attribute__((ext_vector_type(8)));
typedef float f32x2 __attribute__((ext_vector_type(2)));
typedef float f32x4 __attribute__((ext_vector_type(4)));
typedef unsigned int u32x4 __attribute__((ext_vector_type(4)));

__device__ __forceinline__ void gload_lds16(const bf16_t* g, bf16_t* l) {
  __builtin_amdgcn_global_load_lds(
      (const __attribute__((address_space(1))) unsigned int*)g,
      (__attribute__((address_space(3))) unsigned int*)l, 16, 0, 0);
}

// 2^x via v_exp_f32 (no libm)
__device__ __forceinline__ float exp2_hw(float x) {
  float r;
  asm("v_exp_f32 %0, %1" : "=v"(r) : "v"(x));
  return r;
}

#define CVTPK(lo, hi) ({ unsigned r_; \
  asm("v_cvt_pk_bf16_f32 %0, %1, %2" : "=v"(r_) : "v"(lo), "v"(hi)); r_; })

// ---------------- W (K x N fp32) -> W^T (N x K bf16), 4 fused ----------------
__global__ void transpose_cvt4(const float* __restrict__ w0, const float* __restrict__ w1,
                               const float* __restrict__ w2, const float* __restrict__ w3,
                               bf16_t* __restrict__ o0, bf16_t* __restrict__ o1,
                               bf16_t* __restrict__ o2, bf16_t* __restrict__ o3) {
  __shared__ float tile[32][33];
  const float* in = blockIdx.z == 0 ? w0 : blockIdx.z == 1 ? w1 : blockIdx.z == 2 ? w2 : w3;
  bf16_t* out     = blockIdx.z == 0 ? o0 : blockIdx.z == 1 ? o1 : blockIdx.z == 2 ? o2 : o3;
  int n0 = blockIdx.x * 32, k0 = blockIdx.y * 32;
  int tx = threadIdx.x & 31, ty = threadIdx.x >> 5;
  #pragma unroll
  for (int r = ty; r < 32; r += 8)
    tile[r][tx] = in[(size_t)(k0 + r) * ND + n0 + tx];
  __syncthreads();
  #pragma unroll
  for (int r = ty; r < 32; r += 8)
    out[(size_t)(n0 + r) * ND + k0 + tx] = (bf16_t)tile[tx][r];
}

// ---------------- fp32 -> bf16 convert, 3 inputs fused ----------------
__global__ void cvt3(const float* __restrict__ q, const float* __restrict__ k,
                     const float* __restrict__ v, bf16_t* __restrict__ oq,
                     bf16_t* __restrict__ ok, bf16_t* __restrict__ ov) {
  const float* in = blockIdx.y == 0 ? q : blockIdx.y == 1 ? k : v;
  bf16_t* out     = blockIdx.y == 0 ? oq : blockIdx.y == 1 ? ok : ov;
  int i = blockIdx.x * 256 + threadIdx.x;
  float4 vv = ((const float4*)in)[i];
  bf16x4 o;
  o[0] = (bf16_t)vv.x; o[1] = (bf16_t)vv.y; o[2] = (bf16_t)vv.z; o[3] = (bf16_t)vv.w;
  ((bf16x4*)out)[i] = o;
}

// ================= 2-phase 128x128 GEMM core (BK=64, 32 MFMA/wave/step) =================
// 256 thr = 4 waves (2M x 2N); per-wave 64x64 output = acc[4][4] f32x4 (identical
// per-wave schedule to the verified R16 core). LDS 64 KB: 2 dbuf x {A, B} 16 KB
// regions -> 2 blocks/CU (16 waves/CU, doubled TLP). Swizzle: byte col ^=
// ((row&7)<<4); linear dest + pre-swizzled source; 4 staging chunks/thread.
// Per step s (buf b=s&1): phase A: read all B frags + A m0,m1; issue A(s+1)x4
// -> S[b^1][0]; barrier; 16 MFMA; lgkm(0)+barrier. Phase B: read A m2,m3; issue
// B(s+2)x4 -> S[b][1] (race-free after mid-step barrier); barrier; 16 MFMA.
// Close: queue = B(s+1)x4 (oldest), A(s+1)x4, B(s+2)x4 -> vmcnt(4) drains
// B(s+1)+A(s+1); vmcnt(0) at s==NS-2. Prologue: A(0),B(0),B(1) staged; vmcnt(4).
// Grids: QKV (8,64,3) = 1536 = 3 exact rounds @2/CU; O-proj (8,64) = 1 round.
#define GEMM8_CORE(Aptr, Btptr)                                                     \
  const int K = ND;                                                                 \
  const int tid = threadIdx.x, lane = tid & 63, wid = tid >> 6;                     \
  const int wm = wid >> 1, wn = wid & 1;                                            \
  const int lrow = lane & 15, lg = lane >> 4, rb = lg << 2;                         \
  const int tm = blockIdx.y * 128, tn = blockIdx.x * 128;                           \
  const int d0 = tid * 16, d1 = 4096 + tid * 16,                                    \
            d2 = 8192 + tid * 16, d3 = 12288 + tid * 16;                            \
  const int r0s = d0 >> 7, r1s = d1 >> 7, r2s = d2 >> 7, r3s = d3 >> 7;             \
  const int cb0 = (d0 & 127) ^ ((r0s & 7) << 4);                                    \
  const int cb1 = (d1 & 127) ^ ((r1s & 7) << 4);                                    \
  const int cb2 = (d2 & 127) ^ ((r2s & 7) << 4);                                    \
  const int cb3 = (d3 & 127) ^ ((r3s & 7) << 4);                                    \
  const int e0 = d0 >> 1, e1 = d1 >> 1, e2 = d2 >> 1, e3 = d3 >> 1;                 \
  const bf16_t* aC0 = (Aptr) + (size_t)(tm + r0s) * K + (cb0 >> 1);                 \
  const bf16_t* aC1 = (Aptr) + (size_t)(tm + r1s) * K + (cb1 >> 1);                 \
  const bf16_t* aC2 = (Aptr) + (size_t)(tm + r2s) * K + (cb2 >> 1);                 \
  const bf16_t* aC3 = (Aptr) + (size_t)(tm + r3s) * K + (cb3 >> 1);                 \
  const bf16_t* bC0 = (Btptr) + (size_t)(tn + r0s) * K + (cb0 >> 1);                \
  const bf16_t* bC1 = (Btptr) + (size_t)(tn + r1s) * K + (cb1 >> 1);                \
  const bf16_t* bC2 = (Btptr) + (size_t)(tn + r2s) * K + (cb2 >> 1);                \
  const bf16_t* bC3 = (Btptr) + (size_t)(tn + r3s) * K + (cb3 >> 1);                \
  const int swzk = (lrow & 7) << 4;                                                 \
  const int kc0 = (lg * 16) ^ swzk;                                                 \
  const int kc1 = (64 + lg * 16) ^ swzk;                                            \
  const int aBase = wm * 8192 + lrow * 128;                                         \
  const int bBase = wn * 8192 + lrow * 128;                                         \
  f32x4 acc[4][4];                                                                  \
  _Pragma("unroll")                                                                 \
  for (int m = 0; m < 4; ++m)                                                       \
    _Pragma("unroll")                                                               \
    for (int n = 0; n < 4; ++n) {                                                   \
      f32x4 zz = {0.f, 0.f, 0.f, 0.f};                                              \
      acc[m][n] = zz;                                                               \
    }                                                                               \
  gload_lds16(aC0, &S[0][0][0] + e0); gload_lds16(aC1, &S[0][0][0] + e1);           \
  gload_lds16(aC2, &S[0][0][0] + e2); gload_lds16(aC3, &S[0][0][0] + e3);           \
  gload_lds16(bC0, &S[0][1][0] + e0); gload_lds16(bC1, &S[0][1][0] + e1);           \
  gload_lds16(bC2, &S[0][1][0] + e2); gload_lds16(bC3, &S[0][1][0] + e3);           \
  gload_lds16(bC0 + 64, &S[1][1][0] + e0); gload_lds16(bC1 + 64, &S[1][1][0] + e1); \
  gload_lds16(bC2 + 64, &S[1][1][0] + e2); gload_lds16(bC3 + 64, &S[1][1][0] + e3); \
  asm volatile("s_waitcnt vmcnt(4)\n\ts_barrier" ::: "memory");                     \
  const int NS = K / 64;                                                            \
  _Pragma("unroll 1")                                                               \
  for (int s = 0; s < NS; ++s) {                                                    \
    const int b = s & 1;                                                            \
    const char* aReg = (const char*)&S[b][0][0];                                    \
    const char* bReg = (const char*)&S[b][1][0];                                    \
    bf16x8 bfr[4][2];                                                               \
    _Pragma("unroll")                                                               \
    for (int n = 0; n < 4; ++n) {                                                   \
      bfr[n][0] = *(const bf16x8*)(bReg + n * 2048 + bBase + kc0);                  \
      bfr[n][1] = *(const bf16x8*)(bReg + n * 2048 + bBase + kc1);                  \
    }                                                                               \
    bf16x8 afrA[2][2];                                                              \
    afrA[0][0] = *(const bf16x8*)(aReg + 0 * 2048 + aBase + kc0);                   \
    afrA[0][1] = *(const bf16x8*)(aReg + 0 * 2048 + aBase + kc1);                   \
    afrA[1][0] = *(const bf16x8*)(aReg + 1 * 2048 + aBase + kc0);                   \
    afrA[1][1] = *(const bf16x8*)(aReg + 1 * 2048 + aBase + kc1);                   \
    if (s + 1 < NS) {                                                               \
      gload_lds16(aC0 + (s + 1) * 64, &S[b ^ 1][0][0] + e0);                        \
      gload_lds16(aC1 + (s + 1) * 64, &S[b ^ 1][0][0] + e1);                        \
      gload_lds16(aC2 + (s + 1) * 64, &S[b ^ 1][0][0] + e2);                        \
      gload_lds16(aC3 + (s + 1) * 64, &S[b ^ 1][0][0] + e3);                        \
    }                                                                               \
    asm volatile("s_barrier" ::: "memory");                                         \
    __builtin_amdgcn_s_setprio(1);                                                  \
    _Pragma("unroll")                                                               \
    for (int mm = 0; mm < 2; ++mm)                                                  \
      _Pragma("unroll")                                                             \
      for (int n = 0; n < 4; ++n)                                                   \
        _Pragma("unroll")                                                           \
        for (int kk = 0; kk < 2; ++kk)                                              \
          acc[mm][n] = __builtin_amdgcn_mfma_f32_16x16x32_bf16(                     \
              afrA[mm][kk], bfr[n][kk], acc[mm][n], 0, 0, 0);                       \
    __builtin_amdgcn_s_setprio(0);                                                  \
    asm volatile("s_waitcnt lgkmcnt(0)\n\ts_barrier" ::: "memory");                 \
    bf16x8 afrB[2][2];                                                              \
    afrB[0][0] = *(const bf16x8*)(aReg + 2 * 2048 + aBase + kc0);                   \
    afrB[0][1] = *(const bf16x8*)(aReg + 2 * 2048 + aBase + kc1);                   \
    afrB[1][0] = *(const bf16x8*)(aReg + 3 * 2048 + aBase + kc0);                   \
    afrB[1][1] = *(const bf16x8*)(aReg + 3 * 2048 + aBase + kc1);                   \
    if (s + 2 < NS) {                                                               \
      gload_lds16(bC0 + (s + 2) * 64, &S[b][1][0] + e0);                            \
      gload_lds16(bC1 + (s + 2) * 64, &S[b][1][0] + e1);                            \
      gload_lds16(bC2 + (s + 2) * 64, &S[b][1][0] + e2);                            \
      gload_lds16(bC3 + (s + 2) * 64, &S[b][1][0] + e3);                            \
    }                                                                               \
    asm volatile("s_barrier" ::: "memory");                                         \
    __builtin_amdgcn_s_setprio(1);                                                  \
    _Pragma("unroll")                                                               \
    for (int mm = 0; mm < 2; ++mm)                                                  \
      _Pragma("unroll")                                                             \
      for (int n = 0; n < 4; ++n)                                                   \
        _Pragma("unroll")                                                           \
        for (int kk = 0; kk < 2; ++kk)                                              \
          acc[2 + mm][n] = __builtin_amdgcn_mfma_f32_16x16x32_bf16(                 \
              afrB[mm][kk], bfr[n][kk], acc[2 + mm][n], 0, 0, 0);                   \
    __builtin_amdgcn_s_setprio(0);                                                  \
    if (s < NS - 2)                                                                 \
      asm volatile("s_waitcnt vmcnt(4) lgkmcnt(0)\n\ts_barrier" ::: "memory");      \
    else if (s == NS - 2)                                                           \
      asm volatile("s_waitcnt vmcnt(0) lgkmcnt(0)\n\ts_barrier" ::: "memory");      \
    else                                                                            \
      asm volatile("s_waitcnt lgkmcnt(0)" ::: "memory");                            \
  }

// ---------------- QKV instantiation: bf16 head-layout / V^T epilogue ----------------
__global__ __launch_bounds__(256, 2) void gemm8_qkv(
    const bf16_t* __restrict__ Aq, const bf16_t* __restrict__ Ak, const bf16_t* __restrict__ Av,
    const bf16_t* __restrict__ Bq, const bf16_t* __restrict__ Bk, const bf16_t* __restrict__ Bv,
    const float* __restrict__ bq, const float* __restrict__ bk, const float* __restrict__ bv,
    bf16_t* __restrict__ Qh, bf16_t* __restrict__ Kh, bf16_t* __restrict__ Vt,
    float qscale) {
  __shared__ bf16_t S[2][2][8192];
  const int z = blockIdx.z;
  const bf16_t* A    = z == 0 ? Aq : z == 1 ? Ak : Av;
  const bf16_t* Bt   = z == 0 ? Bq : z == 1 ? Bk : Bv;
  const float*  bias = z == 0 ? bq : z == 1 ? bk : bv;
  const float   scale = z == 0 ? qscale : 1.0f;
  bf16_t* outp = z == 0 ? Qh : z == 1 ? Kh : Vt;

  GEMM8_CORE(A, Bt)

  #pragma unroll
  for (int n = 0; n < 4; ++n) {
    const int ncol = tn + wn * 64 + n * 16 + lrow;
    const float bv = bias[ncol];
    const int h = ncol >> 6, dh = ncol & (NDH - 1);
    #pragma unroll
    for (int m = 0; m < 4; ++m) {
      const int m0 = tm + wm * 64 + m * 16 + rb;
      const int bb = m0 >> 11, t0 = m0 & (NT - 1);
      if (z == 2) {
        bf16x4 o;
        #pragma unroll
        for (int r = 0; r < 4; ++r) o[r] = (bf16_t)(acc[m][n][r] + bv);
        size_t idx = ((size_t)(bb * NH + h) * NDH + dh) * NT + t0;
        *(bf16x4*)(outp + idx) = o;
      } else {
        #pragma unroll
        for (int r = 0; r < 4; ++r) {
          float val = (acc[m][n][r] + bv) * scale;
          size_t idx = ((size_t)(bb * NH + h) * NT + t0 + r) * NDH + dh;
          outp[idx] = (bf16_t)val;
        }
      }
    }
  }
}

// ---------------- O-projection instantiation: fp32 row-major epilogue ----------------
__global__ __launch_bounds__(256, 2) void gemm8_out(
    const bf16_t* __restrict__ A, const bf16_t* __restrict__ Bt,
    const float* __restrict__ bias, float* __restrict__ outp) {
  __shared__ bf16_t S[2][2][8192];

  GEMM8_CORE(A, Bt)

  #pragma unroll
  for (int n = 0; n < 4; ++n) {
    const int ncol = tn + wn * 64 + n * 16 + lrow;
    const float bv = bias[ncol];
    #pragma unroll
    for (int m = 0; m < 4; ++m) {
      const int m0 = tm + wm * 64 + m * 16 + rb;
      #pragma unroll
      for (int r = 0; r < 4; ++r)
        outp[(size_t)(m0 + r) * ND + ncol] = acc[m][n][r] + bv;
    }
  }
}

// ---------------- causal flash attention (no-max softmax, MFMA row-sum) ----------------
__device__ __forceinline__ bf16x8 lds_swz_read(const bf16_t* base, int row, int colb) {
  return *(const bf16x8*)((const char*)base + row * 128 + (colb ^ ((row & 7) << 4)));
}

__global__ __launch_bounds__(256) void attn_kernel(
    const bf16_t* __restrict__ Qh, const bf16_t* __restrict__ Kh,
    const bf16_t* __restrict__ Vt, bf16_t* __restrict__ ctx) {
  __shared__ bf16_t Ks[2][64 * 64];
  __shared__ bf16_t Vs[2][64 * 64];
  const int tid  = threadIdx.x;
  const int lane = tid & 63;
  const int wid  = tid >> 6;

  const int work    = (blockIdx.x & 7) * 128 + (blockIdx.x >> 3);
  const int bh      = work >> 4;
  const int pairIdx = work & 15;
  const int b = bh >> 4, h = bh & 15;

  const bf16_t* Qbh = Qh + (size_t)bh * NT * NDH;
  const bf16_t* Kbh = Kh + (size_t)bh * NT * NDH;
  const bf16_t* Vbh = Vt + (size_t)bh * NDH * NT;

  const int lrow = lane & 15;
  const int lg   = lane >> 4;

  bf16x8 ones;
  #pragma unroll
  for (int i = 0; i < 8; ++i) ones[i] = (bf16_t)1.0f;

  const char *kS0, *kS1, *vS0, *vS1;
  {
    int o0 = wid * 1024 + lane * 16;
    int o1 = 4096 + wid * 1024 + lane * 16;
    int r0_ = o0 >> 7, r1_ = o1 >> 7;
    kS0 = (const char*)Kbh + (o0 ^ ((r0_ & 7) << 4));
    kS1 = (const char*)Kbh + (o1 ^ ((r1_ & 7) << 4));
    int c0 = (o0 & 127) ^ ((r0_ & 7) << 4);
    int c1 = (o1 & 127) ^ ((r1_ & 7) << 4);
    vS0 = (const char*)Vbh + (size_t)r0_ * (NT * 2) + c0;
    vS1 = (const char*)Vbh + (size_t)r1_ * (NT * 2) + c1;
  }
  const int ldsOff = wid * 512;

  auto stage = [&](int t, int buf) {
    bf16_t* kb = Ks[buf];
    bf16_t* vb = Vs[buf];
    size_t kOff = (size_t)t * 8192;
    size_t vOff = (size_t)t * 128;
    gload_lds16((const bf16_t*)(kS0 + kOff), kb + ldsOff);
    gload_lds16((const bf16_t*)(kS1 + kOff), kb + 2048 + ldsOff);
    gload_lds16((const bf16_t*)(vS0 + vOff), vb + ldsOff);
    gload_lds16((const bf16_t*)(vS1 + vOff), vb + 2048 + ldsOff);
  };

  #pragma unroll 1
  for (int half = 0; half < 2; ++half) {
    const int qidx = half ? (31 - pairIdx) : pairIdx;
    const int r0   = qidx * 64 + wid * 16;
    const int qg   = r0 + lrow;

    bf16x8 qf0 = *(const bf16x8*)&Qbh[(size_t)(r0 + lrow) * NDH + lg * 8];
    bf16x8 qf1 = *(const bf16x8*)&Qbh[(size_t)(r0 + lrow) * NDH + 32 + lg * 8];

    f32x4 acc[4], accS;
    #pragma unroll
    for (int d = 0; d < 4; ++d) { f32x4 z = {0.f, 0.f, 0.f, 0.f}; acc[d] = z; }
    { f32x4 z = {0.f, 0.f, 0.f, 0.f}; accS = z; }

    __syncthreads();
    stage(0, 0);
    int cur = 0;

    #pragma unroll 1
    for (int t = 0; t <= qidx; ++t) {
      asm volatile("s_waitcnt vmcnt(0)\n\ts_barrier" ::: "memory");
      if (t < qidx) stage(t + 1, cur ^ 1);

      const bf16_t* ksCur = Ks[cur];
      const bf16_t* vsCur = Vs[cur];

      f32x4 sg[4];
      #pragma unroll
      for (int g = 0; g < 4; ++g) { f32x4 z = {0.f, 0.f, 0.f, 0.f}; sg[g] = z; }
      __builtin_amdgcn_s_setprio(1);
      #pragma unroll
      for (int g = 0; g < 4; ++g) {
        bf16x8 kfa = lds_swz_read(ksCur, g * 16 + lrow, lg * 16);
        sg[g] = __builtin_amdgcn_mfma_f32_16x16x32_bf16(kfa, qf0, sg[g], 0, 0, 0);
        bf16x8 kfb = lds_swz_read(ksCur, g * 16 + lrow, 64 + lg * 16);
        sg[g] = __builtin_amdgcn_mfma_f32_16x16x32_bf16(kfb, qf1, sg[g], 0, 0, 0);
      }
      __builtin_amdgcn_s_setprio(0);

      if (t == qidx) {
        const int jb = t * 64;
        #pragma unroll
        for (int g = 0; g < 4; ++g)
          #pragma unroll
          for (int r = 0; r < 4; ++r)
            if (jb + g * 16 + lg * 4 + r > qg) sg[g][r] = -1e30f;
      }

      #pragma unroll
      for (int g = 0; g < 4; ++g)
        #pragma unroll
        for (int r = 0; r < 4; ++r) sg[g][r] = exp2_hw(sg[g][r]);

      unsigned W00 = CVTPK(sg[0][0], sg[0][1]), W01 = CVTPK(sg[0][2], sg[0][3]);
      unsigned W10 = CVTPK(sg[1][0], sg[1][1]), W11 = CVTPK(sg[1][2], sg[1][3]);
      unsigned W20 = CVTPK(sg[2][0], sg[2][1]), W21 = CVTPK(sg[2][2], sg[2][3]);
      unsigned W30 = CVTPK(sg[3][0], sg[3][1]), W31 = CVTPK(sg[3][2], sg[3][3]);
      unsigned w00, w01, w02, w03, w10, w11, w12, w13;
      { unsigned a = W00, bb = W10;
        asm("v_permlane32_swap_b32 %0, %1" : "+v"(a), "+v"(bb));
        asm("v_permlane16_swap_b32 %0, %1" : "+v"(a), "+v"(bb));
        w00 = a; w02 = bb; }
      { unsigned a = W01, bb = W11;
        asm("v_permlane32_swap_b32 %0, %1" : "+v"(a), "+v"(bb));
        asm("v_permlane16_swap_b32 %0, %1" : "+v"(a), "+v"(bb));
        w01 = a; w03 = bb; }
      { unsigned a = W20, bb = W30;
        asm("v_permlane32_swap_b32 %0, %1" : "+v"(a), "+v"(bb));
        asm("v_permlane16_swap_b32 %0, %1" : "+v"(a), "+v"(bb));
        w10 = a; w12 = bb; }
      { unsigned a = W21, bb = W31;
        asm("v_permlane32_swap_b32 %0, %1" : "+v"(a), "+v"(bb));
        asm("v_permlane16_swap_b32 %0, %1" : "+v"(a), "+v"(bb));
        w11 = a; w13 = bb; }
      u32x4 c0 = {w00, w01, w02, w03};
      u32x4 c1 = {w10, w11, w12, w13};
      bf16x8 pf0 = __builtin_bit_cast(bf16x8, c0);
      bf16x8 pf1 = __builtin_bit_cast(bf16x8, c1);

      __builtin_amdgcn_s_setprio(1);
      accS = __builtin_amdgcn_mfma_f32_16x16x32_bf16(ones, pf0, accS, 0, 0, 0);
      #pragma unroll
      for (int d = 0; d < 4; ++d) {
        bf16x8 vf0 = lds_swz_read(vsCur, d * 16 + lrow, lg * 16);
        acc[d] = __builtin_amdgcn_mfma_f32_16x16x32_bf16(vf0, pf0, acc[d], 0, 0, 0);
        bf16x8 vf1 = lds_swz_read(vsCur, d * 16 + lrow, 64 + lg * 16);
        acc[d] = __builtin_amdgcn_mfma_f32_16x16x32_bf16(vf1, pf1, acc[d], 0, 0, 0);
      }
      accS = __builtin_amdgcn_mfma_f32_16x16x32_bf16(ones, pf1, accS, 0, 0, 0);
      __builtin_amdgcn_s_setprio(0);

      cur ^= 1;
    }

    float inv = 1.f / accS[0];
    f32x4 inv4 = {inv, inv, inv, inv};
    size_t orow = ((size_t)b * NT + qg) * ND + h * NDH;
    #pragma unroll
    for (int d2 = 0; d2 < 4; ++d2) {
      f32x4 vv = acc[d2] * inv4;
      bf16x4 o;
      #pragma unroll
      for (int r = 0; r < 4; ++r) o[r] = (bf16_t)vv[r];
      *(bf16x4*)&ctx[orow + d2 * 16 + lg * 4] = o;
    }
  }
}

extern "C" void kernel_launch(void* const* d_in, const int* in_sizes, int n_in,
                              void* d_out, int out_size, void* d_ws, size_t ws_size,
                              hipStream_t stream) {
  const float* q  = (const float*)d_in[0];
  const float* k  = (const float*)d_in[1];
  const float* v  = (const float*)d_in[2];
  const float* Wq = (const float*)d_in[3];
  const float* bq = (const float*)d_in[4];
  const float* Wk = (const float*)d_in[5];
  const float* bk = (const float*)d_in[6];
  const float* Wv = (const float*)d_in[7];
  const float* bv = (const float*)d_in[8];
  const float* Wo = (const float*)d_in[9];
  const float* bo = (const float*)d_in[10];
  float* out = (float*)d_out;

  char* ws = (char*)d_ws;
  const size_t szMK = (size_t)NM * ND * sizeof(bf16_t);  // 16.78 MB
  const size_t szW  = (size_t)ND * ND * sizeof(bf16_t);  // 2 MB
  // Xq,Xk alias d_out (dead until final GEMM); Xv aliases the ctx region.
  bf16_t* Xq  = (bf16_t*)d_out;
  bf16_t* Xk  = Xq + (size_t)NM * ND;
  bf16_t* Xv  = (bf16_t*)(ws);
  bf16_t* ctx = (bf16_t*)(ws);                 // written after Xv is dead
  bf16_t* Qh  = (bf16_t*)(ws + szMK);
  bf16_t* Kh  = (bf16_t*)(ws + 2 * szMK);
  bf16_t* Vt  = (bf16_t*)(ws + 3 * szMK);
  bf16_t* Wqt = (bf16_t*)(ws + 4 * szMK);
  bf16_t* Wkt = (bf16_t*)(ws + 4 * szMK + szW);
  bf16_t* Wvt = (bf16_t*)(ws + 4 * szMK + 2 * szW);
  bf16_t* Wot = (bf16_t*)(ws + 4 * szMK + 3 * szW);

  dim3 tb(256);
  transpose_cvt4<<<dim3(ND / 32, ND / 32, 4), tb, 0, stream>>>(Wq, Wk, Wv, Wo,
                                                               Wqt, Wkt, Wvt, Wot);

  const float qscale = 0.125f * 1.44269504f;   // fold 1/sqrt(DH) and log2(e) into Q

  cvt3<<<dim3(NM * ND / 4 / 256, 3), tb, 0, stream>>>(q, k, v, Xq, Xk, Xv);

  gemm8_qkv<<<dim3(ND / 128, NM / 128, 3), tb, 0, stream>>>(
      Xq, Xk, Xv, Wqt, Wkt, Wvt, bq, bk, bv, Qh, Kh, Vt, qscale);

  attn_kernel<<<dim3(NB * NH * 16), tb, 0, stream>>>(Qh, Kh, Vt, ctx);

  gemm8_out<<<dim3(ND / 128, NM / 128), tb, 0, stream>>>(ctx, Wot, bo, out);
}

// Round 20
// 181.458 us; speedup vs baseline: 1.0240x; 1.0240x over previous
//
#include <hip/hip_runtime.h>
#include <hip/hip_bf16.h>

#define NB 4
#define NT 2048
#define ND 1024
#define NH 16
#define NDH 64
#define NM (NB*NT)   // 8192 rows

typedef __bf16 bf16_t;
typedef bf16_t bf16x4 __attribute__((ext_vector_type(4)));
typedef bf16_t bf16x8 __attribute__((ext_vector_type(8)));
typedef float f32x2 __attribute__((ext_vector_type(2)));
typedef float f32x4 __attribute__((ext_vector_type(4)));
typedef unsigned int u32x4 __attribute__((ext_vector_type(4)));

__device__ __forceinline__ void gload_lds16(const bf16_t* g, bf16_t* l) {
  __builtin_amdgcn_global_load_lds(
      (const __attribute__((address_space(1))) unsigned int*)g,
      (__attribute__((address_space(3))) unsigned int*)l, 16, 0, 0);
}

// 2^x via v_exp_f32 (no libm)
__device__ __forceinline__ float exp2_hw(float x) {
  float r;
  asm("v_exp_f32 %0, %1" : "=v"(r) : "v"(x));
  return r;
}

#define CVTPK(lo, hi) ({ unsigned r_; \
  asm("v_cvt_pk_bf16_f32 %0, %1, %2" : "=v"(r_) : "v"(lo), "v"(hi)); r_; })

// ---------------- W (K x N fp32) -> W^T (N x K bf16), 4 fused ----------------
__global__ void transpose_cvt4(const float* __restrict__ w0, const float* __restrict__ w1,
                               const float* __restrict__ w2, const float* __restrict__ w3,
                               bf16_t* __restrict__ o0, bf16_t* __restrict__ o1,
                               bf16_t* __restrict__ o2, bf16_t* __restrict__ o3) {
  __shared__ float tile[32][33];
  const float* in = blockIdx.z == 0 ? w0 : blockIdx.z == 1 ? w1 : blockIdx.z == 2 ? w2 : w3;
  bf16_t* out     = blockIdx.z == 0 ? o0 : blockIdx.z == 1 ? o1 : blockIdx.z == 2 ? o2 : o3;
  int n0 = blockIdx.x * 32, k0 = blockIdx.y * 32;
  int tx = threadIdx.x & 31, ty = threadIdx.x >> 5;
  #pragma unroll
  for (int r = ty; r < 32; r += 8)
    tile[r][tx] = in[(size_t)(k0 + r) * ND + n0 + tx];
  __syncthreads();
  #pragma unroll
  for (int r = ty; r < 32; r += 8)
    out[(size_t)(n0 + r) * ND + k0 + tx] = (bf16_t)tile[tx][r];
}

// ---------------- fp32 -> bf16 convert, 3 inputs fused ----------------
__global__ void cvt3(const float* __restrict__ q, const float* __restrict__ k,
                     const float* __restrict__ v, bf16_t* __restrict__ oq,
                     bf16_t* __restrict__ ok, bf16_t* __restrict__ ov) {
  const float* in = blockIdx.y == 0 ? q : blockIdx.y == 1 ? k : v;
  bf16_t* out     = blockIdx.y == 0 ? oq : blockIdx.y == 1 ? ok : ov;
  int i = blockIdx.x * 256 + threadIdx.x;
  float4 vv = ((const float4*)in)[i];
  bf16x4 o;
  o[0] = (bf16_t)vv.x; o[1] = (bf16_t)vv.y; o[2] = (bf16_t)vv.z; o[3] = (bf16_t)vv.w;
  ((bf16x4*)out)[i] = o;
}

// ================= 2-phase 128M x 256N GEMM core (BK=64, 16 MFMA/phase) =================
// (R16/R18 verified form.) 512 thr = 8 waves (2M x 4N); per-wave 64x64 = acc[4][4].
// LDS 96 KB: 2 dbuf x {A, B0, B1} 16 KB regions. Swizzle: byte col ^= ((row&7)<<4);
// linear dest + pre-swizzled source. Counted vmcnt(4) per step; vmcnt(0) at NS-2.
#define GEMM8_CORE(Aptr, Btptr)                                                     \
  const int K = ND;                                                                 \
  const int tid = threadIdx.x, lane = tid & 63, wid = tid >> 6;                     \
  const int wm = wid >> 2, wn = wid & 3;                                            \
  const int lrow = lane & 15, lg = lane >> 4, rb = lg << 2;                         \
  const int tm = blockIdx.y * 128, tn = blockIdx.x * 256;                           \
  const int d0 = tid * 16, d1 = 8192 + tid * 16;                                    \
  const int r0s = d0 >> 7, r1s = d1 >> 7;                                           \
  const int cb0 = (d0 & 127) ^ ((r0s & 7) << 4);                                    \
  const int cb1 = (d1 & 127) ^ ((r1s & 7) << 4);                                    \
  const int e0 = d0 >> 1, e1 = d1 >> 1;                                             \
  const bf16_t* aC0 = (Aptr) + (size_t)(tm + r0s) * K + (cb0 >> 1);                 \
  const bf16_t* aC1 = (Aptr) + (size_t)(tm + r1s) * K + (cb1 >> 1);                 \
  const bf16_t* b0C0 = (Btptr) + (size_t)(tn + r0s) * K + (cb0 >> 1);               \
  const bf16_t* b0C1 = (Btptr) + (size_t)(tn + r1s) * K + (cb1 >> 1);               \
  const bf16_t* b1C0 = b0C0 + (size_t)128 * K;                                      \
  const bf16_t* b1C1 = b0C1 + (size_t)128 * K;                                      \
  const int swzk = (lrow & 7) << 4;                                                 \
  const int kc0 = (lg * 16) ^ swzk;                                                 \
  const int kc1 = (64 + lg * 16) ^ swzk;                                            \
  const int aBase = wm * 8192 + lrow * 128;                                         \
  const int bBase = (wn & 1) * 8192 + lrow * 128;                                   \
  f32x4 acc[4][4];                                                                  \
  _Pragma("unroll")                                                                 \
  for (int m = 0; m < 4; ++m)                                                       \
    _Pragma("unroll")                                                               \
    for (int n = 0; n < 4; ++n) {                                                   \
      f32x4 zz = {0.f, 0.f, 0.f, 0.f};                                              \
      acc[m][n] = zz;                                                               \
    }                                                                               \
  gload_lds16(aC0,  &S[0][0][0] + e0); gload_lds16(aC1,  &S[0][0][0] + e1);         \
  gload_lds16(b0C0, &S[0][1][0] + e0); gload_lds16(b0C1, &S[0][1][0] + e1);         \
  gload_lds16(b1C0, &S[0][2][0] + e0); gload_lds16(b1C1, &S[0][2][0] + e1);         \
  gload_lds16(b0C0 + 64, &S[1][1][0] + e0); gload_lds16(b0C1 + 64, &S[1][1][0] + e1);\
  gload_lds16(b1C0 + 64, &S[1][2][0] + e0); gload_lds16(b1C1 + 64, &S[1][2][0] + e1);\
  asm volatile("s_waitcnt vmcnt(4)\n\ts_barrier" ::: "memory");                     \
  const int NS = K / 64;                                                            \
  _Pragma("unroll 1")                                                               \
  for (int s = 0; s < NS; ++s) {                                                    \
    const int b = s & 1;                                                            \
    const char* aReg = (const char*)&S[b][0][0];                                    \
    const char* bReg = (const char*)&S[b][1 + (wn >> 1)][0];                        \
    bf16x8 bfr[4][2];                                                               \
    _Pragma("unroll")                                                               \
    for (int n = 0; n < 4; ++n) {                                                   \
      bfr[n][0] = *(const bf16x8*)(bReg + n * 2048 + bBase + kc0);                  \
      bfr[n][1] = *(const bf16x8*)(bReg + n * 2048 + bBase + kc1);                  \
    }                                                                               \
    bf16x8 afrA[2][2];                                                              \
    afrA[0][0] = *(const bf16x8*)(aReg + 0 * 2048 + aBase + kc0);                   \
    afrA[0][1] = *(const bf16x8*)(aReg + 0 * 2048 + aBase + kc1);                   \
    afrA[1][0] = *(const bf16x8*)(aReg + 1 * 2048 + aBase + kc0);                   \
    afrA[1][1] = *(const bf16x8*)(aReg + 1 * 2048 + aBase + kc1);                   \
    if (s + 1 < NS) {                                                               \
      gload_lds16(aC0 + (s + 1) * 64, &S[b ^ 1][0][0] + e0);                        \
      gload_lds16(aC1 + (s + 1) * 64, &S[b ^ 1][0][0] + e1);                        \
    }                                                                               \
    asm volatile("s_barrier" ::: "memory");                                         \
    __builtin_amdgcn_s_setprio(1);                                                  \
    _Pragma("unroll")                                                               \
    for (int mm = 0; mm < 2; ++mm)                                                  \
      _Pragma("unroll")                                                             \
      for (int n = 0; n < 4; ++n)                                                   \
        _Pragma("unroll")                                                           \
        for (int kk = 0; kk < 2; ++kk)                                              \
          acc[mm][n] = __builtin_amdgcn_mfma_f32_16x16x32_bf16(                     \
              afrA[mm][kk], bfr[n][kk], acc[mm][n], 0, 0, 0);                       \
    __builtin_amdgcn_s_setprio(0);                                                  \
    asm volatile("s_waitcnt lgkmcnt(0)\n\ts_barrier" ::: "memory");                 \
    bf16x8 afrB[2][2];                                                              \
    afrB[0][0] = *(const bf16x8*)(aReg + 2 * 2048 + aBase + kc0);                   \
    afrB[0][1] = *(const bf16x8*)(aReg + 2 * 2048 + aBase + kc1);                   \
    afrB[1][0] = *(const bf16x8*)(aReg + 3 * 2048 + aBase + kc0);                   \
    afrB[1][1] = *(const bf16x8*)(aReg + 3 * 2048 + aBase + kc1);                   \
    if (s + 2 < NS) {                                                               \
      gload_lds16(b0C0 + (s + 2) * 64, &S[b][1][0] + e0);                           \
      gload_lds16(b0C1 + (s + 2) * 64, &S[b][1][0] + e1);                           \
      gload_lds16(b1C0 + (s + 2) * 64, &S[b][2][0] + e0);                           \
      gload_lds16(b1C1 + (s + 2) * 64, &S[b][2][0] + e1);                           \
    }                                                                               \
    asm volatile("s_barrier" ::: "memory");                                         \
    __builtin_amdgcn_s_setprio(1);                                                  \
    _Pragma("unroll")                                                               \
    for (int mm = 0; mm < 2; ++mm)                                                  \
      _Pragma("unroll")                                                             \
      for (int n = 0; n < 4; ++n)                                                   \
        _Pragma("unroll")                                                           \
        for (int kk = 0; kk < 2; ++kk)                                              \
          acc[2 + mm][n] = __builtin_amdgcn_mfma_f32_16x16x32_bf16(                 \
              afrB[mm][kk], bfr[n][kk], acc[2 + mm][n], 0, 0, 0);                   \
    __builtin_amdgcn_s_setprio(0);                                                  \
    if (s < NS - 2)                                                                 \
      asm volatile("s_waitcnt vmcnt(4) lgkmcnt(0)\n\ts_barrier" ::: "memory");      \
    else if (s == NS - 2)                                                           \
      asm volatile("s_waitcnt vmcnt(0) lgkmcnt(0)\n\ts_barrier" ::: "memory");      \
    else                                                                            \
      asm volatile("s_waitcnt lgkmcnt(0)" ::: "memory");                            \
  }

// ---------------- QKV instantiation: bf16 head-layout / V^T epilogue ----------------
__global__ __launch_bounds__(512, 2) void gemm8_qkv(
    const bf16_t* __restrict__ Aq, const bf16_t* __restrict__ Ak, const bf16_t* __restrict__ Av,
    const bf16_t* __restrict__ Bq, const bf16_t* __restrict__ Bk, const bf16_t* __restrict__ Bv,
    const float* __restrict__ bq, const float* __restrict__ bk, const float* __restrict__ bv,
    bf16_t* __restrict__ Qh, bf16_t* __restrict__ Kh, bf16_t* __restrict__ Vt,
    float qscale) {
  __shared__ bf16_t S[2][3][8192];
  const int z = blockIdx.z;
  const bf16_t* A    = z == 0 ? Aq : z == 1 ? Ak : Av;
  const bf16_t* Bt   = z == 0 ? Bq : z == 1 ? Bk : Bv;
  const float*  bias = z == 0 ? bq : z == 1 ? bk : bv;
  const float   scale = z == 0 ? qscale : 1.0f;
  bf16_t* outp = z == 0 ? Qh : z == 1 ? Kh : Vt;

  GEMM8_CORE(A, Bt)

  #pragma unroll
  for (int n = 0; n < 4; ++n) {
    const int ncol = tn + wn * 64 + n * 16 + lrow;
    const float bv = bias[ncol];
    const int h = ncol >> 6, dh = ncol & (NDH - 1);
    #pragma unroll
    for (int m = 0; m < 4; ++m) {
      const int m0 = tm + wm * 64 + m * 16 + rb;
      const int bb = m0 >> 11, t0 = m0 & (NT - 1);
      if (z == 2) {
        bf16x4 o;
        #pragma unroll
        for (int r = 0; r < 4; ++r) o[r] = (bf16_t)(acc[m][n][r] + bv);
        size_t idx = ((size_t)(bb * NH + h) * NDH + dh) * NT + t0;
        *(bf16x4*)(outp + idx) = o;
      } else {
        #pragma unroll
        for (int r = 0; r < 4; ++r) {
          float val = (acc[m][n][r] + bv) * scale;
          size_t idx = ((size_t)(bb * NH + h) * NT + t0 + r) * NDH + dh;
          outp[idx] = (bf16_t)val;
        }
      }
    }
  }
}

// ---------------- O-projection instantiation: fp32 row-major epilogue ----------------
__global__ __launch_bounds__(512, 2) void gemm8_out(
    const bf16_t* __restrict__ A, const bf16_t* __restrict__ Bt,
    const float* __restrict__ bias, float* __restrict__ outp) {
  __shared__ bf16_t S[2][3][8192];

  GEMM8_CORE(A, Bt)

  #pragma unroll
  for (int n = 0; n < 4; ++n) {
    const int ncol = tn + wn * 64 + n * 16 + lrow;
    const float bv = bias[ncol];
    #pragma unroll
    for (int m = 0; m < 4; ++m) {
      const int m0 = tm + wm * 64 + m * 16 + rb;
      #pragma unroll
      for (int r = 0; r < 4; ++r)
        outp[(size_t)(m0 + r) * ND + ncol] = acc[m][n][r] + bv;
    }
  }
}

// ---------------- causal flash attention (no-max softmax, MFMA row-sum) ----------------
// Qh,Kh: (B,H,T,DH) bf16 (Q pre-scaled by 0.125*log2e); Vt: (B,H,DH,T) bf16
// ctx out: (B,T,D) bf16. P = exp2(s) directly (shift-invariance; normalization
// cancels); masked exp2(-1e30) = 0 exactly. Denominator on the MATRIX pipe:
// two extra MFMAs per tile with A = all-ones bf16 give sum_kv P[kv][q]
// replicated across D-rows -> no per-tile VALU sum tree, no epilogue shuffles.
__device__ __forceinline__ bf16x8 lds_swz_read(const bf16_t* base, int row, int colb) {
  return *(const bf16x8*)((const char*)base + row * 128 + (colb ^ ((row & 7) << 4)));
}

__global__ __launch_bounds__(256) void attn_kernel(
    const bf16_t* __restrict__ Qh, const bf16_t* __restrict__ Kh,
    const bf16_t* __restrict__ Vt, bf16_t* __restrict__ ctx) {
  __shared__ bf16_t Ks[2][64 * 64];
  __shared__ bf16_t Vs[2][64 * 64];
  const int tid  = threadIdx.x;
  const int lane = tid & 63;
  const int wid  = tid >> 6;

  // XCD-chunked swizzle (1024 = 8 x 128, bijective)
  const int work    = (blockIdx.x & 7) * 128 + (blockIdx.x >> 3);
  const int bh      = work >> 4;
  const int pairIdx = work & 15;
  const int b = bh >> 4, h = bh & 15;

  const bf16_t* Qbh = Qh + (size_t)bh * NT * NDH;
  const bf16_t* Kbh = Kh + (size_t)bh * NT * NDH;
  const bf16_t* Vbh = Vt + (size_t)bh * NDH * NT;

  const int lrow = lane & 15;
  const int lg   = lane >> 4;

  bf16x8 ones;
  #pragma unroll
  for (int i = 0; i < 8; ++i) ones[i] = (bf16_t)1.0f;

  const char *kS0, *kS1, *vS0, *vS1;
  {
    int o0 = wid * 1024 + lane * 16;
    int o1 = 4096 + wid * 1024 + lane * 16;
    int r0_ = o0 >> 7, r1_ = o1 >> 7;
    kS0 = (const char*)Kbh + (o0 ^ ((r0_ & 7) << 4));
    kS1 = (const char*)Kbh + (o1 ^ ((r1_ & 7) << 4));
    int c0 = (o0 & 127) ^ ((r0_ & 7) << 4);
    int c1 = (o1 & 127) ^ ((r1_ & 7) << 4);
    vS0 = (const char*)Vbh + (size_t)r0_ * (NT * 2) + c0;
    vS1 = (const char*)Vbh + (size_t)r1_ * (NT * 2) + c1;
  }
  const int ldsOff = wid * 512;

  auto stage = [&](int t, int buf) {
    bf16_t* kb = Ks[buf];
    bf16_t* vb = Vs[buf];
    size_t kOff = (size_t)t * 8192;
    size_t vOff = (size_t)t * 128;
    gload_lds16((const bf16_t*)(kS0 + kOff), kb + ldsOff);
    gload_lds16((const bf16_t*)(kS1 + kOff), kb + 2048 + ldsOff);
    gload_lds16((const bf16_t*)(vS0 + vOff), vb + ldsOff);
    gload_lds16((const bf16_t*)(vS1 + vOff), vb + 2048 + ldsOff);
  };

  #pragma unroll 1
  for (int half = 0; half < 2; ++half) {
    const int qidx = half ? (31 - pairIdx) : pairIdx;
    const int r0   = qidx * 64 + wid * 16;
    const int qg   = r0 + lrow;

    bf16x8 qf0 = *(const bf16x8*)&Qbh[(size_t)(r0 + lrow) * NDH + lg * 8];
    bf16x8 qf1 = *(const bf16x8*)&Qbh[(size_t)(r0 + lrow) * NDH + 32 + lg * 8];

    f32x4 acc[4], accS;
    #pragma unroll
    for (int d = 0; d < 4; ++d) { f32x4 z = {0.f, 0.f, 0.f, 0.f}; acc[d] = z; }
    { f32x4 z = {0.f, 0.f, 0.f, 0.f}; accS = z; }

    __syncthreads();
    stage(0, 0);
    int cur = 0;

    #pragma unroll 1
    for (int t = 0; t <= qidx; ++t) {
      asm volatile("s_waitcnt vmcnt(0)\n\ts_barrier" ::: "memory");
      if (t < qidx) stage(t + 1, cur ^ 1);

      const bf16_t* ksCur = Ks[cur];
      const bf16_t* vsCur = Vs[cur];

      f32x4 sg[4];
      #pragma unroll
      for (int g = 0; g < 4; ++g) { f32x4 z = {0.f, 0.f, 0.f, 0.f}; sg[g] = z; }
      __builtin_amdgcn_s_setprio(1);
      #pragma unroll
      for (int g = 0; g < 4; ++g) {
        bf16x8 kfa = lds_swz_read(ksCur, g * 16 + lrow, lg * 16);
        sg[g] = __builtin_amdgcn_mfma_f32_16x16x32_bf16(kfa, qf0, sg[g], 0, 0, 0);
        bf16x8 kfb = lds_swz_read(ksCur, g * 16 + lrow, 64 + lg * 16);
        sg[g] = __builtin_amdgcn_mfma_f32_16x16x32_bf16(kfb, qf1, sg[g], 0, 0, 0);
      }
      __builtin_amdgcn_s_setprio(0);

      if (t == qidx) {
        const int jb = t * 64;
        #pragma unroll
        for (int g = 0; g < 4; ++g)
          #pragma unroll
          for (int r = 0; r < 4; ++r)
            if (jb + g * 16 + lg * 4 + r > qg) sg[g][r] = -1e30f;
      }

      // ---- P = exp2(s) directly ----
      #pragma unroll
      for (int g = 0; g < 4; ++g)
        #pragma unroll
        for (int r = 0; r < 4; ++r) sg[g][r] = exp2_hw(sg[g][r]);

      // ---- P^T -> bf16 B-fragments fully in-register ----
      unsigned W00 = CVTPK(sg[0][0], sg[0][1]), W01 = CVTPK(sg[0][2], sg[0][3]);
      unsigned W10 = CVTPK(sg[1][0], sg[1][1]), W11 = CVTPK(sg[1][2], sg[1][3]);
      unsigned W20 = CVTPK(sg[2][0], sg[2][1]), W21 = CVTPK(sg[2][2], sg[2][3]);
      unsigned W30 = CVTPK(sg[3][0], sg[3][1]), W31 = CVTPK(sg[3][2], sg[3][3]);
      unsigned w00, w01, w02, w03, w10, w11, w12, w13;
      { unsigned a = W00, bb = W10;
        asm("v_permlane32_swap_b32 %0, %1" : "+v"(a), "+v"(bb));
        asm("v_permlane16_swap_b32 %0, %1" : "+v"(a), "+v"(bb));
        w00 = a; w02 = bb; }
      { unsigned a = W01, bb = W11;
        asm("v_permlane32_swap_b32 %0, %1" : "+v"(a), "+v"(bb));
        asm("v_permlane16_swap_b32 %0, %1" : "+v"(a), "+v"(bb));
        w01 = a; w03 = bb; }
      { unsigned a = W20, bb = W30;
        asm("v_permlane32_swap_b32 %0, %1" : "+v"(a), "+v"(bb));
        asm("v_permlane16_swap_b32 %0, %1" : "+v"(a), "+v"(bb));
        w10 = a; w12 = bb; }
      { unsigned a = W21, bb = W31;
        asm("v_permlane32_swap_b32 %0, %1" : "+v"(a), "+v"(bb));
        asm("v_permlane16_swap_b32 %0, %1" : "+v"(a), "+v"(bb));
        w11 = a; w13 = bb; }
      u32x4 c0 = {w00, w01, w02, w03};
      u32x4 c1 = {w10, w11, w12, w13};
      bf16x8 pf0 = __builtin_bit_cast(bf16x8, c0);
      bf16x8 pf1 = __builtin_bit_cast(bf16x8, c1);

      // ---- PV + denominator on the matrix pipe ----
      __builtin_amdgcn_s_setprio(1);
      accS = __builtin_amdgcn_mfma_f32_16x16x32_bf16(ones, pf0, accS, 0, 0, 0);
      #pragma unroll
      for (int d = 0; d < 4; ++d) {
        bf16x8 vf0 = lds_swz_read(vsCur, d * 16 + lrow, lg * 16);
        acc[d] = __builtin_amdgcn_mfma_f32_16x16x32_bf16(vf0, pf0, acc[d], 0, 0, 0);
        bf16x8 vf1 = lds_swz_read(vsCur, d * 16 + lrow, 64 + lg * 16);
        acc[d] = __builtin_amdgcn_mfma_f32_16x16x32_bf16(vf1, pf1, acc[d], 0, 0, 0);
      }
      accS = __builtin_amdgcn_mfma_f32_16x16x32_bf16(ones, pf1, accS, 0, 0, 0);
      __builtin_amdgcn_s_setprio(0);

      cur ^= 1;
    }

    // ---- epilogue: lsum already replicated in every lane (accS[0]) ----
    float inv = 1.f / accS[0];
    f32x4 inv4 = {inv, inv, inv, inv};
    size_t orow = ((size_t)b * NT + qg) * ND + h * NDH;
    #pragma unroll
    for (int d2 = 0; d2 < 4; ++d2) {
      f32x4 vv = acc[d2] * inv4;
      bf16x4 o;
      #pragma unroll
      for (int r = 0; r < 4; ++r) o[r] = (bf16_t)vv[r];
      *(bf16x4*)&ctx[orow + d2 * 16 + lg * 4] = o;
    }
  }
}

extern "C" void kernel_launch(void* const* d_in, const int* in_sizes, int n_in,
                              void* d_out, int out_size, void* d_ws, size_t ws_size,
                              hipStream_t stream) {
  const float* q  = (const float*)d_in[0];
  const float* k  = (const float*)d_in[1];
  const float* v  = (const float*)d_in[2];
  const float* Wq = (const float*)d_in[3];
  const float* bq = (const float*)d_in[4];
  const float* Wk = (const float*)d_in[5];
  const float* bk = (const float*)d_in[6];
  const float* Wv = (const float*)d_in[7];
  const float* bv = (const float*)d_in[8];
  const float* Wo = (const float*)d_in[9];
  const float* bo = (const float*)d_in[10];
  float* out = (float*)d_out;

  char* ws = (char*)d_ws;
  const size_t szMK = (size_t)NM * ND * sizeof(bf16_t);  // 16.78 MB
  const size_t szW  = (size_t)ND * ND * sizeof(bf16_t);  // 2 MB
  // Xq,Xk alias d_out (dead until final GEMM); Xv aliases the ctx region.
  bf16_t* Xq  = (bf16_t*)d_out;
  bf16_t* Xk  = Xq + (size_t)NM * ND;
  bf16_t* Xv  = (bf16_t*)(ws);
  bf16_t* ctx = (bf16_t*)(ws);                 // written after Xv is dead
  bf16_t* Qh  = (bf16_t*)(ws + szMK);
  bf16_t* Kh  = (bf16_t*)(ws + 2 * szMK);
  bf16_t* Vt  = (bf16_t*)(ws + 3 * szMK);
  bf16_t* Wqt = (bf16_t*)(ws + 4 * szMK);
  bf16_t* Wkt = (bf16_t*)(ws + 4 * szMK + szW);
  bf16_t* Wvt = (bf16_t*)(ws + 4 * szMK + 2 * szW);
  bf16_t* Wot = (bf16_t*)(ws + 4 * szMK + 3 * szW);

  dim3 tb(256);
  transpose_cvt4<<<dim3(ND / 32, ND / 32, 4), tb, 0, stream>>>(Wq, Wk, Wv, Wo,
                                                               Wqt, Wkt, Wvt, Wot);

  const float qscale = 0.125f * 1.44269504f;   // fold 1/sqrt(DH) and log2(e) into Q

  cvt3<<<dim3(NM * ND / 4 / 256, 3), tb, 0, stream>>>(q, k, v, Xq, Xk, Xv);

  gemm8_qkv<<<dim3(ND / 256, NM / 128, 3), dim3(512), 0, stream>>>(
      Xq, Xk, Xv, Wqt, Wkt, Wvt, bq, bk, bv, Qh, Kh, Vt, qscale);

  attn_kernel<<<dim3(NB * NH * 16), tb, 0, stream>>>(Qh, Kh, Vt, ctx);

  gemm8_out<<<dim3(ND / 256, NM / 128), dim3(512), 0, stream>>>(ctx, Wot, bo, out);
}